// Round 3
// baseline (1993.601 us; speedup 1.0000x reference)
//
#include <hip/hip_runtime.h>

#define TMAIN 1024
#define TFUT  64
#define TTOT  (TMAIN + TFUT)

__device__ __forceinline__ float sig_(float x) {
    return 1.0f / (1.0f + __expf(-x));
}
__device__ __forceinline__ float tanh_(float x) {
    x = fminf(15.0f, fmaxf(-15.0f, x));
    float e = __expf(-2.0f * x);
    return (1.0f - e) / (1.0f + e);
}

// One block per batch element. 256 threads = 4 waves.
// Thread owns gate-row `row` of layer1 (64 w) and layer2 (128 w) in VGPRs.
// Partition: wave wv owns hidden units [16*wv, 16*wv+16); lane = q*16 + (unit%16)
// where q = gate index (i,f,g,o). All 4 gates of a unit are in ONE wave ->
// gate exchange via __shfl_xor (no barrier). Only 2 barriers per timestep.
__global__ __launch_bounds__(256, 2)
void lstm2_kernel(const float* __restrict__ x,
                  const float* __restrict__ Wih1,
                  const float* __restrict__ Whh1,
                  const float* __restrict__ bih1,
                  const float* __restrict__ bhh1,
                  const float* __restrict__ Wih2,
                  const float* __restrict__ Whh2,
                  const float* __restrict__ bih2,
                  const float* __restrict__ bhh2,
                  const float* __restrict__ Wl,
                  const float* __restrict__ bl,
                  float* __restrict__ out)
{
    const int b    = blockIdx.x;
    const int tid  = threadIdx.x;
    const int wv   = tid >> 6;
    const int lane = tid & 63;
    const int q    = lane >> 4;              // gate 0..3 (i,f,g,o)
    const int unit = (wv << 4) + (lane & 15); // hidden unit 0..63
    const int row  = (q << 6) + unit;         // gate-row 0..255

    // ---- weights in registers (192 VGPRs) ----
    float4 w1[16], w2a[16], w2b[16];
    const float4* W1r  = reinterpret_cast<const float4*>(Whh1 + row * 64);
    const float4* W2ar = reinterpret_cast<const float4*>(Wih2 + row * 64);
    const float4* W2br = reinterpret_cast<const float4*>(Whh2 + row * 64);
#pragma unroll
    for (int j = 0; j < 16; ++j) { w1[j] = W1r[j]; w2a[j] = W2ar[j]; w2b[j] = W2br[j]; }

    const float wih1r = Wih1[row];
    const float bias1 = bih1[row] + bhh1[row];
    const float bias2 = bih2[row] + bhh2[row];
    const float wlu   = Wl[unit];
    const float bl0   = bl[0];

    __shared__ __align__(16) float h1buf[2][64];
    __shared__ __align__(16) float h2buf[2][64];
    __shared__ __align__(16) float psum[4];

    if (tid < 64) {
        h1buf[0][tid] = 0.0f; h1buf[1][tid] = 0.0f;
        h2buf[0][tid] = 0.0f; h2buf[1][tid] = 0.0f;
    }
    __syncthreads();

    float c1 = 0.0f, c2 = 0.0f, xv = 0.0f;
    const float* xb = x + b * TMAIN;
    float* ob = out + b * TTOT;

    for (int s = 0; s < TTOT; ++s) {
        const int p = s & 1;
        const float x_t = (s < TMAIN) ? xb[s] : xv;

        // ---------- layer 1 gate row ----------
        float acc = fmaf(wih1r, x_t, bias1);
        const float4* h1o = reinterpret_cast<const float4*>(h1buf[p]);
#pragma unroll
        for (int j = 0; j < 16; ++j) {
            float4 h = h1o[j];
            acc = fmaf(w1[j].x, h.x, acc);
            acc = fmaf(w1[j].y, h.y, acc);
            acc = fmaf(w1[j].z, h.z, acc);
            acc = fmaf(w1[j].w, h.w, acc);
        }
        float gv = (q == 2) ? tanh_(acc) : sig_(acc);
        // gather all 4 gates of this unit (in-wave butterfly)
        float v1 = __shfl_xor(gv, 16, 64);
        float v2 = __shfl_xor(gv, 32, 64);
        float v3 = __shfl_xor(v1, 32, 64);
        float gi = (q == 0) ? gv : (q == 1) ? v1 : (q == 2) ? v2 : v3;
        float gf = (q == 1) ? gv : (q == 0) ? v1 : (q == 3) ? v2 : v3;
        float gg = (q == 2) ? gv : (q == 3) ? v1 : (q == 0) ? v2 : v3;
        float go = (q == 3) ? gv : (q == 2) ? v1 : (q == 1) ? v2 : v3;
        c1 = fmaf(gf, c1, gi * gg);
        const float h1n = go * tanh_(c1);
        if (q == 0) h1buf[p ^ 1][unit] = h1n;
        __syncthreads();                       // barrier 1: h1_new visible

        // ---------- layer 2 gate row ----------
        acc = bias2;
        const float4* h1v = reinterpret_cast<const float4*>(h1buf[p ^ 1]);
        const float4* h2o = reinterpret_cast<const float4*>(h2buf[p]);
#pragma unroll
        for (int j = 0; j < 16; ++j) {
            float4 h = h1v[j];
            acc = fmaf(w2a[j].x, h.x, acc);
            acc = fmaf(w2a[j].y, h.y, acc);
            acc = fmaf(w2a[j].z, h.z, acc);
            acc = fmaf(w2a[j].w, h.w, acc);
        }
#pragma unroll
        for (int j = 0; j < 16; ++j) {
            float4 h = h2o[j];
            acc = fmaf(w2b[j].x, h.x, acc);
            acc = fmaf(w2b[j].y, h.y, acc);
            acc = fmaf(w2b[j].z, h.z, acc);
            acc = fmaf(w2b[j].w, h.w, acc);
        }
        gv = (q == 2) ? tanh_(acc) : sig_(acc);
        v1 = __shfl_xor(gv, 16, 64);
        v2 = __shfl_xor(gv, 32, 64);
        v3 = __shfl_xor(v1, 32, 64);
        gi = (q == 0) ? gv : (q == 1) ? v1 : (q == 2) ? v2 : v3;
        gf = (q == 1) ? gv : (q == 0) ? v1 : (q == 3) ? v2 : v3;
        gg = (q == 2) ? gv : (q == 3) ? v1 : (q == 0) ? v2 : v3;
        go = (q == 3) ? gv : (q == 2) ? v1 : (q == 1) ? v2 : v3;
        c2 = fmaf(gf, c2, gi * gg);
        const float h2n = go * tanh_(c2);
        if (q == 0) h2buf[p ^ 1][unit] = h2n;

        // ---------- output: out = Wl . h2_new + bl ----------
        float pv = (q == 0) ? wlu * h2n : 0.0f;
#pragma unroll
        for (int m = 1; m < 64; m <<= 1) pv += __shfl_xor(pv, m, 64);
        if (lane == 0) psum[wv] = pv;
        __syncthreads();                       // barrier 2: h2_new + psum visible

        const float4 ps = *reinterpret_cast<const float4*>(psum);
        xv = ps.x + ps.y + ps.z + ps.w + bl0;  // uniform; feeds future phase
        if (tid == 0) ob[s] = xv;
    }
}

extern "C" void kernel_launch(void* const* d_in, const int* in_sizes, int n_in,
                              void* d_out, int out_size, void* d_ws, size_t ws_size,
                              hipStream_t stream)
{
    const float* xx   = (const float*)d_in[0];
    const float* Wih1 = (const float*)d_in[1];
    const float* Whh1 = (const float*)d_in[2];
    const float* bih1 = (const float*)d_in[3];
    const float* bhh1 = (const float*)d_in[4];
    const float* Wih2 = (const float*)d_in[5];
    const float* Whh2 = (const float*)d_in[6];
    const float* bih2 = (const float*)d_in[7];
    const float* bhh2 = (const float*)d_in[8];
    const float* Wl   = (const float*)d_in[9];
    const float* bl   = (const float*)d_in[10];
    float* out = (float*)d_out;

    lstm2_kernel<<<dim3(512), dim3(256), 0, stream>>>(
        xx, Wih1, Whh1, bih1, bhh1, Wih2, Whh2, bih2, bhh2, Wl, bl, out);
}